// Round 11
// baseline (2093.324 us; speedup 1.0000x reference)
//
#include <hip/hip_runtime.h>

// File-scope: forbid implicit fma contraction (keeps every a*b+c as two
// single-rounded IEEE ops, matching the numpy reference bit-for-bit).
#pragma clang fp contract(off)

#define NPOINT 2048
#define NSAMPLE 32
#define NPTS 8192
#define NB 4
#define CH 16
#define FPS_THREADS 512
#define PTS_PER_THREAD (NPTS / FPS_THREADS) /* 16 */
#define PAIRS (PTS_PER_THREAD / 2)          /* 8 */

typedef unsigned long long u64;
typedef float v2f __attribute__((ext_vector_type(2)));

// Output layout (flat float32, concatenated in reference return order)
#define OFF_NEWXYZ 0
#define OFF_NEWPTS (NB * NPOINT * 3)                          /* 24576 */
#define OFF_IDX (OFF_NEWPTS + NB * NPOINT * NSAMPLE * CH)     /* 4218880 */
#define OFF_GXYZ (OFF_IDX + NB * NPOINT * NSAMPLE)            /* 4481024 */

template <int CTRL>
__device__ __forceinline__ float dpp_fmax(float v) {
  // bound_ctrl=true -> 0-fill; distances are >= 0 so 0 is a safe identity.
  int o = __builtin_amdgcn_update_dpp(0, __float_as_int(v), CTRL, 0xf, 0xf, true);
  return fmaxf(v, __int_as_float(o));
}

// ---------------- FPS: one block per batch, sequential 2048-step scan ------
// Reference semantics: idxs[0]=0; each step: dists=min(dists,|p-p_last|^2),
// next = argmax(dists) with FIRST-index tie-break. Op order mirrored:
// (dx*dx + dy*dy) + dz*dz, single-rounded IEEE, no fma contraction.
//
// R10 model (validated against 4 rounds): with lockstepped waves, wall/iter ~=
// waves_per_simd * inst_per_wave * 2cyc + exposed LDS-chain + barrier. So:
//  - 512 threads (2 waves/SIMD, 16 pts/thread) halves the issue multiplier
//    and halves the replication of per-wave reduce overhead.
//  - cross-wave argmax via ONE LDS atomicMax(u64) into a mod-3 ring of key
//    slots (read / atomic-target / reset per iter) -> removes the DPP slot
//    reduce + ballot + readlanes from the serial chain; one barrier/iter.
// Key = (distbits<<32) | (8191-idx): unsigned max => max dist, tie => lowest
// index (exact jnp.argmax tie-break). Duplicate atomics from tied lanes are
// safe (max of tied keys = lowest idx). Contiguous ownership keeps
// (wave,lane,j) order == index order.
__global__ __launch_bounds__(FPS_THREADS)
__attribute__((amdgpu_waves_per_eu(2))) void fps_kernel(
    const float* __restrict__ in, float* __restrict__ out) {
  __shared__ float4 lpxyz[NPTS];      // 128 KB; winner coords: 1 ds_read_b128
  __shared__ float newb[NPOINT * 3];  // 24 KB newxyz staging
  __shared__ u64 kslot[3];            // mod-3 ring of argmax key slots

  const int b = blockIdx.x;
  const int tid = threadIdx.x;
  const float* base = in + (size_t)b * NPTS * CH;

  v2f pxv[PAIRS], pyv[PAIRS], pzv[PAIRS], dv[PAIRS];
#pragma unroll
  for (int jp = 0; jp < PAIRS; ++jp) {
    int p0 = tid * PTS_PER_THREAD + 2 * jp;
    float4 r0 = *reinterpret_cast<const float4*>(base + (size_t)p0 * CH);
    float4 r1 = *reinterpret_cast<const float4*>(base + (size_t)(p0 + 1) * CH);
    pxv[jp] = (v2f){r0.x, r1.x};
    pyv[jp] = (v2f){r0.y, r1.y};
    pzv[jp] = (v2f){r0.z, r1.z};
    lpxyz[p0] = r0;
    lpxyz[p0 + 1] = r1;
    dv[jp] = (v2f){__builtin_inff(), __builtin_inff()};
  }
  if (tid == 0) {
    kslot[0] = ((u64)0x7f800000u << 32) | 8191u;  // point 0 wins iter 0
    kslot[1] = 0;
    kslot[2] = 0;
  }

  int rd = 0, at = 1, rs = 2;  // read / atomic-target / reset slot indices
  for (int it = 0; it < NPOINT; ++it) {
    __syncthreads();  // orders: prior atomics/reset/init before reads below
    // Winner of this iteration: broadcast LDS reads (all lanes same addr).
    const u64 k = kslot[rd];
    const int gi = 8191 - (int)(unsigned)k;  // low 32 bits = 8191-idx
    const float4 g = lpxyz[gi];
    const float gx = g.x, gy = g.y, gz = g.z;
    if (tid == 0) {
      kslot[rs] = 0;  // recycle slot consumed 2 iters ago (barrier-separated)
      newb[it * 3 + 0] = gx;
      newb[it * 3 + 1] = gy;
      newb[it * 3 + 2] = gz;
    }
    // Distance update (packed pairs; exact IEEE per-element) + value max.
    float bestv = -1.0f;
#pragma unroll
    for (int jp = 0; jp < PAIRS; ++jp) {
      v2f dx = pxv[jp] - gx;
      v2f dy = pyv[jp] - gy;
      v2f dz = pzv[jp] - gz;
      v2f nd = (dx * dx + dy * dy) + dz * dz;
      v2f dn = {fminf(dv[jp].x, nd.x), fminf(dv[jp].y, nd.y)};
      dv[jp] = dn;
      bestv = fmaxf(fmaxf(bestv, dn.x), dn.y);  // max3 pattern
    }
    // Recover lowest j achieving bestv (descending scan -> lowest wins).
    const float* df = (const float*)dv;
    int bestj = 0;
#pragma unroll
    for (int jj = PTS_PER_THREAD - 1; jj >= 0; --jj)
      if (df[jj] == bestv) bestj = jj;
    const int besti = tid * PTS_PER_THREAD + bestj;
    // Wave max via 6 f32 DPP rounds; all lanes matching the wave max issue
    // the atomic (ties collapse to lowest idx via the key encoding).
    float wm = bestv;
    wm = dpp_fmax<0x111>(wm);  // row_shr:1
    wm = dpp_fmax<0x112>(wm);  // row_shr:2
    wm = dpp_fmax<0x114>(wm);  // row_shr:4
    wm = dpp_fmax<0x118>(wm);  // row_shr:8
    wm = dpp_fmax<0x142>(wm);  // row_bcast15
    wm = dpp_fmax<0x143>(wm);  // row_bcast31
    const float swm =
        __int_as_float(__builtin_amdgcn_readlane(__float_as_int(wm), 63));
    if (bestv == swm) {
      u64 key = ((u64)__float_as_uint(bestv) << 32) | (8191u - (unsigned)besti);
      atomicMax(&kslot[at], key);
    }
    // Rotate the ring: read <- atomic-target <- reset <- read.
    const int t = rd;
    rd = at;
    at = rs;
    rs = t;
  }
  __syncthreads();
  // Dump staged newxyz to global once.
  float* ob = out + OFF_NEWXYZ + (size_t)b * NPOINT * 3;
  for (int i = tid; i < NPOINT * 3; i += FPS_THREADS) ob[i] = newb[i];
}

// ---------------- Ball query + group: one wave per query -------------------
__device__ __forceinline__ void write_slot(float* __restrict__ out,
                                           const float* __restrict__ base,
                                           int b, int qi, int s, int p,
                                           float4 r0, float qx, float qy,
                                           float qz) {
  float dx = __fsub_rn(r0.x, qx);
  float dy = __fsub_rn(r0.y, qy);
  float dz = __fsub_rn(r0.z, qz);
  size_t qs = (size_t)b * NPOINT + qi;
  out[OFF_IDX + qs * NSAMPLE + s] = (float)p;  // idx stored as float32
  float* g = out + OFF_GXYZ + (qs * NSAMPLE + s) * 3;
  g[0] = dx;
  g[1] = dy;
  g[2] = dz;
  const float* row = base + (size_t)p * CH;
  float4 r1 = *reinterpret_cast<const float4*>(row + 4);
  float4 r2 = *reinterpret_cast<const float4*>(row + 8);
  float4 r3 = *reinterpret_cast<const float4*>(row + 12);
  float* np_ = out + OFF_NEWPTS + (qs * NSAMPLE + s) * CH;
  *reinterpret_cast<float4*>(np_ + 0) = make_float4(dx, dy, dz, r0.w);
  *reinterpret_cast<float4*>(np_ + 4) = r1;
  *reinterpret_cast<float4*>(np_ + 8) = r2;
  *reinterpret_cast<float4*>(np_ + 12) = r3;
}

__global__ __launch_bounds__(256) void ballq_kernel(
    const float* __restrict__ in, float* __restrict__ out) {
  const int lane = threadIdx.x & 63;
  const int qid = blockIdx.x * 4 + (threadIdx.x >> 6);
  const int b = qid >> 11;    // / NPOINT
  const int qi = qid & 2047;  // % NPOINT
  const float* base = in + (size_t)b * NPTS * CH;
  const float* q = out + OFF_NEWXYZ + ((size_t)b * NPOINT + qi) * 3;
  float qx = q[0], qy = q[1], qz = q[2];
  // Mirror reference: d2 = sum(q*q) + sum(p*p) - 2*(q . p)
  float qn = __fadd_rn(__fadd_rn(__fmul_rn(qx, qx), __fmul_rn(qy, qy)),
                       __fmul_rn(qz, qz));

  int cnt = 0;
  int first = 0;
  bool have_first = false;
  for (int chunk = 0; chunk < NPTS / 64 && cnt < NSAMPLE; ++chunk) {
    int p = chunk * 64 + lane;
    float4 r0 = *reinterpret_cast<const float4*>(base + (size_t)p * CH);
    float pn =
        __fadd_rn(__fadd_rn(__fmul_rn(r0.x, r0.x), __fmul_rn(r0.y, r0.y)),
                  __fmul_rn(r0.z, r0.z));
    float dot =
        __fadd_rn(__fadd_rn(__fmul_rn(qx, r0.x), __fmul_rn(qy, r0.y)),
                  __fmul_rn(qz, r0.z));
    float d2 = __fsub_rn(__fadd_rn(qn, pn), __fmul_rn(2.0f, dot));
    bool in_r = d2 < 1.0f;  // RADIUS^2
    unsigned long long mask = __ballot(in_r);
    if (!have_first && mask) {
      first = chunk * 64 + __builtin_ctzll(mask);
      have_first = true;
    }
    int pos = cnt + __popcll(mask & ((1ull << lane) - 1ull));
    if (in_r && pos < NSAMPLE) write_slot(out, base, b, qi, pos, p, r0, qx, qy, qz);
    cnt += __popcll(mask);
  }
  if (cnt < NSAMPLE) {
    // Pad remaining slots with the first in-radius index (reference fill rule).
    int s = cnt + lane;
    if (s < NSAMPLE) {
      float4 r0 = *reinterpret_cast<const float4*>(base + (size_t)first * CH);
      write_slot(out, base, b, qi, s, first, r0, qx, qy, qz);
    }
  }
}

extern "C" void kernel_launch(void* const* d_in, const int* in_sizes, int n_in,
                              void* d_out, int out_size, void* d_ws,
                              size_t ws_size, hipStream_t stream) {
  (void)in_sizes;
  (void)n_in;
  (void)out_size;
  (void)d_ws;
  (void)ws_size;
  const float* in = (const float*)d_in[0];
  float* out = (float*)d_out;
  fps_kernel<<<NB, FPS_THREADS, 0, stream>>>(in, out);
  ballq_kernel<<<(NB * NPOINT) / 4, 256, 0, stream>>>(in, out);
}

// Round 13
// 1917.219 us; speedup vs baseline: 1.0919x; 1.0919x over previous
//
#include <hip/hip_runtime.h>

// File-scope: forbid implicit fma contraction (keeps every a*b+c as two
// single-rounded IEEE ops, matching the numpy reference bit-for-bit).
#pragma clang fp contract(off)

#define NPOINT 2048
#define NSAMPLE 32
#define NPTS 8192
#define NB 4
#define CH 16
#define FPS_THREADS 256
#define PTS_PER_THREAD (NPTS / FPS_THREADS) /* 32 */

typedef unsigned long long u64;

// Output layout (flat float32, concatenated in reference return order)
#define OFF_NEWXYZ 0
#define OFF_NEWPTS (NB * NPOINT * 3)                          /* 24576 */
#define OFF_IDX (OFF_NEWPTS + NB * NPOINT * NSAMPLE * CH)     /* 4218880 */
#define OFF_GXYZ (OFF_IDX + NB * NPOINT * NSAMPLE)            /* 4481024 */

template <int CTRL>
__device__ __forceinline__ float dpp_fmax(float v) {
  // bound_ctrl=true -> 0-fill; distances are >= 0 so 0 is a safe identity.
  int o = __builtin_amdgcn_update_dpp(0, __float_as_int(v), CTRL, 0xf, 0xf, true);
  return fmaxf(v, __int_as_float(o));
}

// ---------------- FPS: one block per batch, sequential 2048-step scan ------
// Reference semantics: idxs[0]=0; each step: dists=min(dists,|p-p_last|^2),
// next = argmax(dists) with FIRST-index tie-break. Op order mirrored:
// (dx*dx + dy*dy) + dz*dz, single-rounded IEEE, no fma contraction.
//
// R11 post-mortem: 1024t is issue-bound (82% VALU busy), 512t is
// latency-exposed (59%) — both stall at ~2250 cyc/iter. R12 corner: 256
// threads = 1 wave/SIMD, ALL point state in registers (px/py/pz/d[32] = 128
// VGPRs; waves_per_eu(1) grants up to 512 — the attribute was proven honored
// in R11 when VGPR_Count moved 52->88). Overhead is replicated x4 not x16,
// no LDS in the distance loop, cross-wave argmax = one LDS atomicMax per
// wave into the R11-verified mod-3 ring of key slots (one barrier/iter).
// Key = (distbits<<32)|(8191-idx): max => max dist, tie => lowest index
// (exact jnp.argmax tie-break). Contiguous ownership (thread t owns points
// t*32..t*32+31) keeps (wave,lane,j) order == global index order.
__global__ __launch_bounds__(FPS_THREADS)
__attribute__((amdgpu_waves_per_eu(1))) void fps_kernel(
    const float* __restrict__ in, float* __restrict__ out) {
  __shared__ float4 lpxyz[NPTS];      // 128 KB; winner coords: 1 ds_read_b128
  __shared__ float newb[NPOINT * 3];  // 24 KB newxyz staging
  __shared__ u64 kslot[3];            // mod-3 ring of argmax key slots

  const int b = blockIdx.x;
  const int tid = threadIdx.x;
  const int lane = tid & 63;
  const float* base = in + (size_t)b * NPTS * CH;

  float px[PTS_PER_THREAD], py[PTS_PER_THREAD], pz[PTS_PER_THREAD],
      d[PTS_PER_THREAD];
#pragma unroll
  for (int j = 0; j < PTS_PER_THREAD; ++j) {
    int p = tid * PTS_PER_THREAD + j;
    float4 r = *reinterpret_cast<const float4*>(base + (size_t)p * CH);
    px[j] = r.x;
    py[j] = r.y;
    pz[j] = r.z;
    lpxyz[p] = r;
    d[j] = __builtin_inff();
  }
  if (tid == 0) {
    kslot[0] = ((u64)0x7f800000u << 32) | 8191u;  // point 0 wins iter 0
    kslot[1] = 0;
    kslot[2] = 0;
  }

  int rd = 0, at = 1, rs = 2;  // read / atomic-target / reset slot indices
  for (int it = 0; it < NPOINT; ++it) {
    __syncthreads();  // orders: prior atomics/reset/init before reads below
    // Winner of this iteration: broadcast LDS reads (all lanes same addr).
    const u64 k = kslot[rd];
    const int gi = 8191 - (int)(unsigned)k;  // low 32 bits = 8191-idx
    const float4 g = lpxyz[gi];
    const float gx = g.x, gy = g.y, gz = g.z;
    if (tid == 0) {
      kslot[rs] = 0;  // recycle slot consumed 2 iters ago (barrier-separated)
      newb[it * 3 + 0] = gx;
      newb[it * 3 + 1] = gy;
      newb[it * 3 + 2] = gz;
    }
    // Distance update + incremental argmax, fully register-resident.
    // Per point: 3 sub, 3 mul, 2 add, 1 min, 1 cmp, 1 cndmask(j inline), 1 max.
    float bestv = -1.0f;
    int bestj = 0;
#pragma unroll
    for (int j = 0; j < PTS_PER_THREAD; ++j) {
      float dx = px[j] - gx;
      float dy = py[j] - gy;
      float dz = pz[j] - gz;
      float nd = (dx * dx + dy * dy) + dz * dz;
      float dn = fminf(d[j], nd);
      d[j] = dn;
      bestj = (dn > bestv) ? j : bestj;  // strict '>': lowest j wins ties
      bestv = fmaxf(bestv, dn);
    }
    const int besti = tid * PTS_PER_THREAD + bestj;
    // Wave reduce: f32 DPP max -> lane 63; ballot picks lowest lane (= lowest
    // index under contiguous ownership); one atomic per wave into the ring.
    float wm = bestv;
    wm = dpp_fmax<0x111>(wm);  // row_shr:1
    wm = dpp_fmax<0x112>(wm);  // row_shr:2
    wm = dpp_fmax<0x114>(wm);  // row_shr:4
    wm = dpp_fmax<0x118>(wm);  // row_shr:8
    wm = dpp_fmax<0x142>(wm);  // row_bcast15
    wm = dpp_fmax<0x143>(wm);  // row_bcast31
    const float swm =
        __int_as_float(__builtin_amdgcn_readlane(__float_as_int(wm), 63));
    const u64 wbal = __ballot(bestv == swm);
    const int wl = (int)__builtin_ctzll(wbal);
    const int widx = __builtin_amdgcn_readlane(besti, wl);
    if (lane == 0) {
      u64 key = ((u64)__float_as_uint(swm) << 32) | (8191u - (unsigned)widx);
      atomicMax(&kslot[at], key);
    }
    // Rotate the ring: read <- atomic-target <- reset <- read.
    const int t = rd;
    rd = at;
    at = rs;
    rs = t;
  }
  __syncthreads();
  // Dump staged newxyz to global once.
  float* ob = out + OFF_NEWXYZ + (size_t)b * NPOINT * 3;
  for (int i = tid; i < NPOINT * 3; i += FPS_THREADS) ob[i] = newb[i];
}

// ---------------- Ball query + group: one wave per query -------------------
__device__ __forceinline__ void write_slot(float* __restrict__ out,
                                           const float* __restrict__ base,
                                           int b, int qi, int s, int p,
                                           float4 r0, float qx, float qy,
                                           float qz) {
  float dx = __fsub_rn(r0.x, qx);
  float dy = __fsub_rn(r0.y, qy);
  float dz = __fsub_rn(r0.z, qz);
  size_t qs = (size_t)b * NPOINT + qi;
  out[OFF_IDX + qs * NSAMPLE + s] = (float)p;  // idx stored as float32
  float* g = out + OFF_GXYZ + (qs * NSAMPLE + s) * 3;
  g[0] = dx;
  g[1] = dy;
  g[2] = dz;
  const float* row = base + (size_t)p * CH;
  float4 r1 = *reinterpret_cast<const float4*>(row + 4);
  float4 r2 = *reinterpret_cast<const float4*>(row + 8);
  float4 r3 = *reinterpret_cast<const float4*>(row + 12);
  float* np_ = out + OFF_NEWPTS + (qs * NSAMPLE + s) * CH;
  *reinterpret_cast<float4*>(np_ + 0) = make_float4(dx, dy, dz, r0.w);
  *reinterpret_cast<float4*>(np_ + 4) = r1;
  *reinterpret_cast<float4*>(np_ + 8) = r2;
  *reinterpret_cast<float4*>(np_ + 12) = r3;
}

__global__ __launch_bounds__(256) void ballq_kernel(
    const float* __restrict__ in, float* __restrict__ out) {
  const int lane = threadIdx.x & 63;
  const int qid = blockIdx.x * 4 + (threadIdx.x >> 6);
  const int b = qid >> 11;    // / NPOINT
  const int qi = qid & 2047;  // % NPOINT
  const float* base = in + (size_t)b * NPTS * CH;
  const float* q = out + OFF_NEWXYZ + ((size_t)b * NPOINT + qi) * 3;
  float qx = q[0], qy = q[1], qz = q[2];
  // Mirror reference: d2 = sum(q*q) + sum(p*p) - 2*(q . p)
  float qn = __fadd_rn(__fadd_rn(__fmul_rn(qx, qx), __fmul_rn(qy, qy)),
                       __fmul_rn(qz, qz));

  int cnt = 0;
  int first = 0;
  bool have_first = false;
  for (int chunk = 0; chunk < NPTS / 64 && cnt < NSAMPLE; ++chunk) {
    int p = chunk * 64 + lane;
    float4 r0 = *reinterpret_cast<const float4*>(base + (size_t)p * CH);
    float pn =
        __fadd_rn(__fadd_rn(__fmul_rn(r0.x, r0.x), __fmul_rn(r0.y, r0.y)),
                  __fmul_rn(r0.z, r0.z));
    float dot =
        __fadd_rn(__fadd_rn(__fmul_rn(qx, r0.x), __fmul_rn(qy, r0.y)),
                  __fmul_rn(qz, r0.z));
    float d2 = __fsub_rn(__fadd_rn(qn, pn), __fmul_rn(2.0f, dot));
    bool in_r = d2 < 1.0f;  // RADIUS^2
    unsigned long long mask = __ballot(in_r);
    if (!have_first && mask) {
      first = chunk * 64 + __builtin_ctzll(mask);
      have_first = true;
    }
    int pos = cnt + __popcll(mask & ((1ull << lane) - 1ull));
    if (in_r && pos < NSAMPLE) write_slot(out, base, b, qi, pos, p, r0, qx, qy, qz);
    cnt += __popcll(mask);
  }
  if (cnt < NSAMPLE) {
    // Pad remaining slots with the first in-radius index (reference fill rule).
    int s = cnt + lane;
    if (s < NSAMPLE) {
      float4 r0 = *reinterpret_cast<const float4*>(base + (size_t)first * CH);
      write_slot(out, base, b, qi, s, first, r0, qx, qy, qz);
    }
  }
}

extern "C" void kernel_launch(void* const* d_in, const int* in_sizes, int n_in,
                              void* d_out, int out_size, void* d_ws,
                              size_t ws_size, hipStream_t stream) {
  (void)in_sizes;
  (void)n_in;
  (void)out_size;
  (void)d_ws;
  (void)ws_size;
  const float* in = (const float*)d_in[0];
  float* out = (float*)d_out;
  fps_kernel<<<NB, FPS_THREADS, 0, stream>>>(in, out);
  ballq_kernel<<<(NB * NPOINT) / 4, 256, 0, stream>>>(in, out);
}